// Round 2
// baseline (699.824 us; speedup 1.0000x reference)
//
#include <hip/hip_runtime.h>
#include <cstddef>

// Critic_43104291783486 — round 2: fix GEMM2 K-tile offset bug (hbuf column
// index was missing kt*16 — GEMM2 multiplied all W2 tiles against hidden
// cols 0..15). Plus int64/int32 hedge for local_edges.
// B=256, N=256, H=256, F=64, NNB=4, HEADS=3, S=15.
// phase1: per (node n, 64-row batch block) fused MLPs -> Q[B][N][F] in d_ws (16MB).
// phase2: neighbor gather + subset-min + chi + mean -> out[B][N].

#define BN 256   // nodes
#define BB 256   // batch
#define HD 256   // hidden
#define FD 64    // feature out

// ---------------- phase 1 helpers ----------------

// X tile: 16 k x 64 rows, transposed in LDS with stride 68 (pad kills bank conflicts)
__device__ __forceinline__ void stageX_load(const float* __restrict__ xs, int b0, int n, int kOff,
                                            int tid, float4& xr) {
  int row = tid >> 2;
  int kq  = (tid & 3) << 2;
  xr = *(const float4*)(xs + (size_t)(b0 + row) * (BN * HD) + (size_t)n * HD + kOff + kq);
}
__device__ __forceinline__ void stageX_write(float* Xt, int tid, const float4& xr) {
  int row = tid >> 2;
  int kq  = (tid & 3) << 2;
  Xt[(kq + 0) * 68 + row] = xr.x;
  Xt[(kq + 1) * 68 + row] = xr.y;
  Xt[(kq + 2) * 68 + row] = xr.z;
  Xt[(kq + 3) * 68 + row] = xr.w;
}
// W1 tile: 16 x 256 row-major (contiguous from global)
__device__ __forceinline__ void stageW_load(const float* __restrict__ Wk, int tid, float4 wr[4]) {
#pragma unroll
  for (int i = 0; i < 4; ++i) wr[i] = *(const float4*)(Wk + (i * 256 + tid) * 4);
}
__device__ __forceinline__ void stageW_write(float* Ws, int tid, const float4 wr[4]) {
#pragma unroll
  for (int i = 0; i < 4; ++i) *(float4*)(Ws + (i * 256 + tid) * 4) = wr[i];
}

// 64x256 output tile, 256 threads: thread (ty=tid>>5, tx=tid&31) owns rows
// {ty*4..+3, 32+ty*4..+3} x cols {tx*4..+3, 128+tx*4..+3}  (8x8 acc, 4 FLOP/LDS-f32)
__device__ __forceinline__ void gemm1_step(const float* Xt, const float* Ws,
                                           int tx, int ty, float acc[8][8]) {
#pragma unroll
  for (int k = 0; k < 16; ++k) {
    float4 a0 = *(const float4*)(Xt + k * 68 + ty * 4);
    float4 a1 = *(const float4*)(Xt + k * 68 + 32 + ty * 4);
    float4 b0 = *(const float4*)(Ws + k * 256 + tx * 4);
    float4 b1 = *(const float4*)(Ws + k * 256 + 128 + tx * 4);
    float av[8] = {a0.x, a0.y, a0.z, a0.w, a1.x, a1.y, a1.z, a1.w};
    float bv[8] = {b0.x, b0.y, b0.z, b0.w, b1.x, b1.y, b1.z, b1.w};
#pragma unroll
    for (int i = 0; i < 8; ++i)
#pragma unroll
      for (int j = 0; j < 8; ++j)
        acc[i][j] = fmaf(av[i], bv[j], acc[i][j]);
  }
}

// C(64xHD) = X(64xK) * W(KxHD), K = NK*16, X source switches obs->act at k=256
__device__ __forceinline__ void run_gemm1(int NK, const float* xs0, const float* xs1,
                                          const float* W1base, int b0, int n, int tid,
                                          int tx, int ty,
                                          float* Xt0, float* Xt1, float* Ws0, float* Ws1,
                                          float acc[8][8]) {
  float4 xr; float4 wr[4];
  stageX_load(xs0, b0, n, 0, tid, xr);
  stageW_load(W1base, tid, wr);
  stageX_write(Xt0, tid, xr);
  stageW_write(Ws0, tid, wr);
  for (int kt = 0; kt < NK; ++kt) {
    float* Xtc = (kt & 1) ? Xt1 : Xt0;
    float* Wsc = (kt & 1) ? Ws1 : Ws0;
    float* Xtn = (kt & 1) ? Xt0 : Xt1;
    float* Wsn = (kt & 1) ? Ws0 : Ws1;
    __syncthreads();                       // buffer `cur` fully written by all waves
    bool more = (kt + 1 < NK);
    if (more) {                            // issue next-tile global loads early
      int kOff = (kt + 1) * 16;
      const float* xs = (kOff < 256) ? xs0 : xs1;
      stageX_load(xs, b0, n, kOff & 255, tid, xr);
      stageW_load(W1base + (size_t)(kt + 1) * 16 * 256, tid, wr);
    }
    gemm1_step(Xtc, Wsc, tx, ty, acc);     // HBM latency hides under 1024 FMA
    if (more) { stageX_write(Xtn, tid, xr); stageW_write(Wsn, tid, wr); }
  }
  __syncthreads();
}

// GEMM2: C(64x64) = h(64x256) * W2(256x64); thread (tr=tid>>4, tc=tid&15) owns 4x4
// hbk = hbuf + kt*16 (column base of this K tile), row stride 260.
__device__ __forceinline__ void gemm2_step(const float* hbk, const float* Ws,
                                           int tr, int tc, float acc2[4][4]) {
#pragma unroll
  for (int k = 0; k < 16; ++k) {
    float a0 = hbk[(tr * 4 + 0) * 260 + k];
    float a1 = hbk[(tr * 4 + 1) * 260 + k];
    float a2 = hbk[(tr * 4 + 2) * 260 + k];
    float a3 = hbk[(tr * 4 + 3) * 260 + k];
    float4 bq = *(const float4*)(Ws + k * 64 + tc * 4);
    float bv[4] = {bq.x, bq.y, bq.z, bq.w};
#pragma unroll
    for (int j = 0; j < 4; ++j) {
      acc2[0][j] = fmaf(a0, bv[j], acc2[0][j]);
      acc2[1][j] = fmaf(a1, bv[j], acc2[1][j]);
      acc2[2][j] = fmaf(a2, bv[j], acc2[2][j]);
      acc2[3][j] = fmaf(a3, bv[j], acc2[3][j]);
    }
  }
}

__device__ __forceinline__ void run_gemm2(const float* W2base, int tid, int tr, int tc,
                                          float* Ws0, float* Ws1, const float* hb,
                                          float acc2[4][4]) {
  float4 wr = *(const float4*)(W2base + tid * 4);   // 16x64 tile = 256 float4
  *(float4*)(Ws0 + tid * 4) = wr;
  for (int kt = 0; kt < 16; ++kt) {
    float* Wsc = (kt & 1) ? Ws1 : Ws0;
    float* Wsn = (kt & 1) ? Ws0 : Ws1;
    __syncthreads();
    bool more = (kt + 1 < 16);
    if (more) wr = *(const float4*)(W2base + (size_t)(kt + 1) * 16 * 64 + tid * 4);
    gemm2_step(hb + kt * 16, Wsc, tr, tc, acc2);   // FIX: K-tile column offset
    if (more) *(float4*)(Wsn + tid * 4) = wr;
  }
  __syncthreads();
}

__global__ __launch_bounds__(256, 1) void phase1_kernel(
    const float* __restrict__ obs, const float* __restrict__ act,
    const float* __restrict__ V_W1, const float* __restrict__ V_b1,
    const float* __restrict__ V_W2, const float* __restrict__ V_b2,
    const float* __restrict__ A_W1, const float* __restrict__ A_b1,
    const float* __restrict__ A_W2, const float* __restrict__ A_b2,
    float* __restrict__ Q) {
  __shared__ float WsB[2][16 * 256];   // 32 KB  W1/W2 tiles (double-buffered)
  __shared__ float XtB[2][16 * 68];    // 8.5 KB X tiles, transposed, padded
  __shared__ float hbuf[64 * 260];     // 65 KB  hidden activations, padded
  // total 105.5 KB -> 1 WG/CU (gfx950 allows up to 160 KB/WG)

  int tid = threadIdx.x;
  int tx = tid & 31, ty = tid >> 5;    // GEMM1 mapping
  int tr = tid >> 4, tc = tid & 15;    // GEMM2 mapping

  // XCD-grouped swizzle: the 4 b-blocks of one node land on the same XCD slot
  int bid = blockIdx.x;
  int chunk = bid >> 5, pos = bid & 31;
  int n  = chunk * 8 + (pos & 7);
  int b0 = (pos >> 3) * 64;

  float acc[8][8];
  float acc2[4][4];
#pragma unroll
  for (int i = 0; i < 4; ++i)
#pragma unroll
    for (int j = 0; j < 4; ++j) acc2[i][j] = 0.f;

  // ---------- V branch ----------
#pragma unroll
  for (int i = 0; i < 8; ++i)
#pragma unroll
    for (int j = 0; j < 8; ++j) acc[i][j] = 0.f;
  run_gemm1(16, obs, obs, V_W1 + (size_t)n * HD * HD, b0, n, tid, tx, ty,
            XtB[0], XtB[1], WsB[0], WsB[1], acc);
  {
    const float* b1p = V_b1 + n * HD;
    float4 bb0 = *(const float4*)(b1p + tx * 4);
    float4 bb1 = *(const float4*)(b1p + 128 + tx * 4);
    float bb[8] = {bb0.x, bb0.y, bb0.z, bb0.w, bb1.x, bb1.y, bb1.z, bb1.w};
#pragma unroll
    for (int ih = 0; ih < 2; ++ih)
#pragma unroll
      for (int i = 0; i < 4; ++i) {
        int row = ih * 32 + ty * 4 + i;
        float4 h0, h1;
        h0.x = fmaxf(acc[ih * 4 + i][0] + bb[0], 0.f);
        h0.y = fmaxf(acc[ih * 4 + i][1] + bb[1], 0.f);
        h0.z = fmaxf(acc[ih * 4 + i][2] + bb[2], 0.f);
        h0.w = fmaxf(acc[ih * 4 + i][3] + bb[3], 0.f);
        h1.x = fmaxf(acc[ih * 4 + i][4] + bb[4], 0.f);
        h1.y = fmaxf(acc[ih * 4 + i][5] + bb[5], 0.f);
        h1.z = fmaxf(acc[ih * 4 + i][6] + bb[6], 0.f);
        h1.w = fmaxf(acc[ih * 4 + i][7] + bb[7], 0.f);
        *(float4*)(hbuf + row * 260 + tx * 4) = h0;
        *(float4*)(hbuf + row * 260 + 128 + tx * 4) = h1;
      }
  }
  __syncthreads();
  run_gemm2(V_W2 + (size_t)n * HD * FD, tid, tr, tc, WsB[0], WsB[1], hbuf, acc2);

  // ---------- A branch (accumulates into same acc2 => Q = V + A) ----------
#pragma unroll
  for (int i = 0; i < 8; ++i)
#pragma unroll
    for (int j = 0; j < 8; ++j) acc[i][j] = 0.f;
  run_gemm1(32, obs, act, A_W1 + (size_t)n * 2 * HD * HD, b0, n, tid, tx, ty,
            XtB[0], XtB[1], WsB[0], WsB[1], acc);
  {
    const float* b1p = A_b1 + n * HD;
    float4 bb0 = *(const float4*)(b1p + tx * 4);
    float4 bb1 = *(const float4*)(b1p + 128 + tx * 4);
    float bb[8] = {bb0.x, bb0.y, bb0.z, bb0.w, bb1.x, bb1.y, bb1.z, bb1.w};
#pragma unroll
    for (int ih = 0; ih < 2; ++ih)
#pragma unroll
      for (int i = 0; i < 4; ++i) {
        int row = ih * 32 + ty * 4 + i;
        float4 h0, h1;
        h0.x = fmaxf(acc[ih * 4 + i][0] + bb[0], 0.f);
        h0.y = fmaxf(acc[ih * 4 + i][1] + bb[1], 0.f);
        h0.z = fmaxf(acc[ih * 4 + i][2] + bb[2], 0.f);
        h0.w = fmaxf(acc[ih * 4 + i][3] + bb[3], 0.f);
        h1.x = fmaxf(acc[ih * 4 + i][4] + bb[4], 0.f);
        h1.y = fmaxf(acc[ih * 4 + i][5] + bb[5], 0.f);
        h1.z = fmaxf(acc[ih * 4 + i][6] + bb[6], 0.f);
        h1.w = fmaxf(acc[ih * 4 + i][7] + bb[7], 0.f);
        *(float4*)(hbuf + row * 260 + tx * 4) = h0;
        *(float4*)(hbuf + row * 260 + 128 + tx * 4) = h1;
      }
  }
  __syncthreads();
  run_gemm2(A_W2 + (size_t)n * HD * FD, tid, tr, tc, WsB[0], WsB[1], hbuf, acc2);

  // ---------- store Q = acc2 + V_b2 + A_b2 ----------
  {
    float4 c0 = *(const float4*)(V_b2 + n * FD + tc * 4);
    float4 c1 = *(const float4*)(A_b2 + n * FD + tc * 4);
#pragma unroll
    for (int i = 0; i < 4; ++i) {
      int b = b0 + tr * 4 + i;
      float4 q;
      q.x = acc2[i][0] + c0.x + c1.x;
      q.y = acc2[i][1] + c0.y + c1.y;
      q.z = acc2[i][2] + c0.z + c1.z;
      q.w = acc2[i][3] + c0.w + c1.w;
      *(float4*)(Q + (size_t)b * (BN * FD) + n * FD + tc * 4) = q;
    }
  }
}

// ---------------- phase 2: gather + subset-min + chi + mean ----------------
__global__ __launch_bounds__(256) void phase2_kernel(const float* __restrict__ Q,
                                                     const float* __restrict__ chi_m,
                                                     const int* __restrict__ le,
                                                     float* __restrict__ out) {
  int b = blockIdx.x;
  int n = threadIdx.x;
  // local_edges is declared int64 in the reference. If the harness kept it
  // int64, the int32 view interleaves zero high-words. Detect via the known
  // deterministic layout: centers = arange(N), so int32 layout has le[5]==1
  // (center of node 1) while int64 layout has le[5]==0 (high word of n0's
  // second neighbor... any high word is 0 since values < 2^31).
  int step = (le[5] == 1) ? 1 : 2;           // words per logical element
  const int* e = le + n * 5 * step;
  int c  = e[0 * step] & (BN - 1);
  int n0 = e[1 * step] & (BN - 1);
  int n1 = e[2 * step] & (BN - 1);
  int n2 = e[3 * step] & (BN - 1);
  int n3 = e[4 * step] & (BN - 1);
  const float* ch = chi_m + n * 45;           // (HEADS=3, S=15)
  float cm[15];
#pragma unroll
  for (int s = 0; s < 15; ++s) cm[s] = (ch[s] + ch[15 + s] + ch[30 + s]) * (1.f / 3.f);
  const float* qb = Q + (size_t)b * (BN * FD);
  const float* q0 = qb + n0 * FD;
  const float* q1 = qb + n1 * FD;
  const float* q2 = qb + n2 * FD;
  const float* q3 = qb + n3 * FD;
  const float* qc = qb + c * FD;
  float acc = 0.f;
#pragma unroll
  for (int f = 0; f < FD; f += 4) {
    float4 v0 = *(const float4*)(q0 + f);
    float4 v1 = *(const float4*)(q1 + f);
    float4 v2 = *(const float4*)(q2 + f);
    float4 v3 = *(const float4*)(q3 + f);
    float4 vc = *(const float4*)(qc + f);
    const float* p0 = (const float*)&v0;
    const float* p1 = (const float*)&v1;
    const float* p2 = (const float*)&v2;
    const float* p3 = (const float*)&v3;
    const float* pc = (const float*)&vc;
#pragma unroll
    for (int u = 0; u < 4; ++u) {
      float a = p0[u], bq = p1[u], cq = p2[u], d = p3[u];
      float m01 = fminf(a, bq), m02 = fminf(a, cq), m03 = fminf(a, d);
      float m12 = fminf(bq, cq), m13 = fminf(bq, d), m23 = fminf(cq, d);
      float m012 = fminf(m01, cq), m013 = fminf(m01, d);
      float m023 = fminf(m02, d),  m123 = fminf(m12, d);
      float m0123 = fminf(m01, m23);
      // subset index s-1 (s = bitmask over neighbors {0,1,2,3}, s=1..15)
      float chi = cm[0] * a   + cm[1] * bq   + cm[2] * m01  + cm[3] * cq
                + cm[4] * m02 + cm[5] * m12  + cm[6] * m012 + cm[7] * d
                + cm[8] * m03 + cm[9] * m13  + cm[10] * m013 + cm[11] * m23
                + cm[12] * m023 + cm[13] * m123 + cm[14] * m0123;
      acc += chi + pc[u];
    }
  }
  out[b * BN + n] = acc * (1.f / 64.f);
}

extern "C" void kernel_launch(void* const* d_in, const int* in_sizes, int n_in,
                              void* d_out, int out_size, void* d_ws, size_t ws_size,
                              hipStream_t stream) {
  (void)in_sizes; (void)n_in; (void)out_size; (void)ws_size;
  const float* obs  = (const float*)d_in[0];
  const float* act  = (const float*)d_in[1];
  const float* V_W1 = (const float*)d_in[2];
  const float* V_b1 = (const float*)d_in[3];
  const float* V_W2 = (const float*)d_in[4];
  const float* V_b2 = (const float*)d_in[5];
  const float* A_W1 = (const float*)d_in[6];
  const float* A_b1 = (const float*)d_in[7];
  const float* A_W2 = (const float*)d_in[8];
  const float* A_b2 = (const float*)d_in[9];
  const float* chim = (const float*)d_in[10];
  const int*   le   = (const int*)d_in[11];
  float* Q   = (float*)d_ws;                  // 16 MB scratch: Q[B][N][F]
  float* out = (float*)d_out;

  phase1_kernel<<<dim3(1024), dim3(256), 0, stream>>>(obs, act, V_W1, V_b1, V_W2, V_b2,
                                                      A_W1, A_b1, A_W2, A_b2, Q);
  phase2_kernel<<<dim3(256), dim3(256), 0, stream>>>(Q, chim, le, out);
}

// Round 3
// 146.894 us; speedup vs baseline: 4.7642x; 4.7642x over previous
//
#include <hip/hip_runtime.h>
#include <cstddef>

// Critic_43104291783486 — round 3: fp16 MFMA rewrite of phase1.
// fp32 inputs converted to fp16 during LDS staging; accumulate in f32 via
// v_mfma_f32_16x16x32_f16. Error budget ~1e-4 << 1.57e-3 threshold.
// Block = (node n, 64 batch rows). 256 thr / 4 waves. 2 blocks/CU (77 KB LDS).

#define BN 256   // nodes
#define BB 256   // batch
#define HD 256   // hidden
#define FD 64    // feature out

#define XS 40    // X lds row stride (fp16): 32 k + 8 pad -> 80 B (16B-aligned, 2-way banks)
#define WS 260   // W1 lds cols per khi slab (256 + 4 pad)
#define HS 264   // h lds row stride (256 + 8 pad) -> 528 B rows, 16B-aligned

typedef _Float16 f16x8 __attribute__((ext_vector_type(8)));
typedef float f32x4 __attribute__((ext_vector_type(4)));

// ---------- staging: X tile (64 rows x 32 k) ----------
// thread t: row = t>>2, k-oct = (t&3)*8 ; 4 lanes cover 128B contiguous global.
__device__ __forceinline__ void x_load(const float* __restrict__ src, int b0, int n,
                                       int kOff, int tid, float4 xr[2]) {
  int row = tid >> 2, ko = (tid & 3) * 8;
  const float* p = src + (size_t)(b0 + row) * (BN * HD) + n * HD + kOff + ko;
  xr[0] = *(const float4*)p;
  xr[1] = *(const float4*)(p + 4);
}
__device__ __forceinline__ void x_write(_Float16* Xl, int tid, const float4 xr[2]) {
  int row = tid >> 2, ko = (tid & 3) * 8;
  const float* f = (const float*)xr;
  f16x8 v;
#pragma unroll
  for (int i = 0; i < 8; ++i) v[i] = (_Float16)f[i];
  *(f16x8*)(Xl + row * XS + ko) = v;   // 16B-aligned (XS*2=80)
}

// ---------- staging: W1 tile (32 k x 256 cols), transposed to k-contiguous ----------
// LDS layout [khi=4][WS cols][klo=8] fp16. thread t: khi=t>>6, col=t&63 (+cg*64).
// Global: per k-row, 64 lanes read 64 consecutive floats (256B coalesced).
// LDS write: lanes write consecutive 16B slots -> conflict-free.
__device__ __forceinline__ void w_load(const float* __restrict__ Wg, int kt, int tid,
                                       float wr[4][8]) {
  int khi = tid >> 6, col = tid & 63;
  const float* base = Wg + (size_t)(kt * 32 + khi * 8) * 256 + col;
#pragma unroll
  for (int cg = 0; cg < 4; ++cg)
#pragma unroll
    for (int r = 0; r < 8; ++r)
      wr[cg][r] = base[r * 256 + cg * 64];
}
__device__ __forceinline__ void w_write(_Float16* Wl, int tid, const float wr[4][8]) {
  int khi = tid >> 6, col = tid & 63;
#pragma unroll
  for (int cg = 0; cg < 4; ++cg) {
    f16x8 v;
#pragma unroll
    for (int r = 0; r < 8; ++r) v[r] = (_Float16)wr[cg][r];
    *(f16x8*)(Wl + ((size_t)khi * WS + cg * 64 + col) * 8) = v;
  }
}

// ---------- GEMM1 k32-step: C(64x256) += X(64x32) * W(32x256) ----------
// wave-grid 1M x 4N: wave w owns cols w*64..w*64+63. Per wave: 4 A + 4 B reads, 16 MFMA.
// A-frag: row = m*16 + (l&15), k = (l>>4)*8 + j (k-contiguous in LDS row).
// B-frag: col = Nbase + nf*16 + (l&15), k = (l>>4)*8 + j ([khi][col][klo] layout).
__device__ __forceinline__ void g1_step(const _Float16* Xl, const _Float16* Wl,
                                        int lrow, int lk, int Nbase, f32x4 acc[4][4]) {
  f16x8 a[4], b[4];
#pragma unroll
  for (int m = 0; m < 4; ++m)
    a[m] = *(const f16x8*)(Xl + (m * 16 + lrow) * XS + lk * 8);
#pragma unroll
  for (int nf = 0; nf < 4; ++nf)
    b[nf] = *(const f16x8*)(Wl + ((size_t)lk * WS + Nbase + nf * 16 + lrow) * 8);
#pragma unroll
  for (int m = 0; m < 4; ++m)
#pragma unroll
    for (int nf = 0; nf < 4; ++nf)
      acc[m][nf] = __builtin_amdgcn_mfma_f32_16x16x32_f16(a[m], b[nf], acc[m][nf], 0, 0, 0);
}

// C(64xHD) = X(64xK) * W(KxHD); K = NK*32; X switches obs->act at k=256 (A branch).
template <int NK>
__device__ __forceinline__ void run_gemm1(const float* xs0, const float* xs1,
                                          const float* Wg, int b0, int n, int tid,
                                          int lrow, int lk, int Nbase,
                                          _Float16* Xl0, _Float16* Xl1,
                                          _Float16* Wl0, _Float16* Wl1, f32x4 acc[4][4]) {
  float4 xr[2];
  float wr[4][8];
  x_load(xs0, b0, n, 0, tid, xr);
  w_load(Wg, 0, tid, wr);
  x_write(Xl0, tid, xr);
  w_write(Wl0, tid, wr);
#pragma unroll 2
  for (int kt = 0; kt < NK; ++kt) {
    _Float16* Xc = (kt & 1) ? Xl1 : Xl0;
    _Float16* Wc = (kt & 1) ? Wl1 : Wl0;
    _Float16* Xn = (kt & 1) ? Xl0 : Xl1;
    _Float16* Wn = (kt & 1) ? Wl0 : Wl1;
    __syncthreads();                       // cur buffer fully written by all waves
    bool more = (kt + 1 < NK);
    if (more) {                            // issue next-tile global loads early
      int kOff = (kt + 1) * 32;
      const float* xs = (kOff < 256) ? xs0 : xs1;
      x_load(xs, b0, n, kOff & 255, tid, xr);
      w_load(Wg, kt + 1, tid, wr);
    }
    g1_step(Xc, Wc, lrow, lk, Nbase, acc); // HBM latency hides under MFMA+reads
    if (more) { x_write(Xn, tid, xr); w_write(Wn, tid, wr); }
  }
  __syncthreads();
}

// ---------- h epilogue: relu(C1 + b1) -> fp16 LDS [row][k] ----------
__device__ __forceinline__ void h_write(_Float16* hl, const float* __restrict__ b1g,
                                        int w, int lrow, int lk, const f32x4 acc[4][4]) {
#pragma unroll
  for (int nf = 0; nf < 4; ++nf) {
    int col = w * 64 + nf * 16 + lrow;
    float bv = b1g[col];
#pragma unroll
    for (int m = 0; m < 4; ++m)
#pragma unroll
      for (int r = 0; r < 4; ++r) {
        int row = m * 16 + lk * 4 + r;     // C/D: row=(lane>>4)*4+reg, col=lane&15
        hl[row * HS + col] = (_Float16)fmaxf(acc[m][nf][r] + bv, 0.f);
      }
  }
}

// ---------- W2 stage: full 256x64 -> [khi=32][68][8] fp16 ----------
__device__ __forceinline__ void w2_stage(const float* __restrict__ W2g, int tid,
                                         _Float16* Wl) {
  int khiL = tid >> 6, col = tid & 63;
#pragma unroll 1
  for (int s = 0; s < 8; ++s) {
    int khi = s * 4 + khiL;
    f16x8 v;
#pragma unroll
    for (int r = 0; r < 8; ++r) v[r] = (_Float16)W2g[(khi * 8 + r) * 64 + col];
    *(f16x8*)(Wl + ((size_t)khi * 68 + col) * 8) = v;
  }
}

// ---------- GEMM2: C2(64x64) += h(64x256) * W2(256x64) ----------
// wave-grid 2M x 2N: wave tile 32 rows x 32 cols; acc2[2][2] persists across V+A.
__device__ __forceinline__ void run_gemm2(const _Float16* hl, const _Float16* Wl,
                                          int wm, int wn, int lrow, int lk,
                                          f32x4 acc2[2][2]) {
#pragma unroll 1
  for (int s = 0; s < 8; ++s) {
    f16x8 a[2], b[2];
#pragma unroll
    for (int mf = 0; mf < 2; ++mf)
      a[mf] = *(const f16x8*)(hl + (wm * 32 + mf * 16 + lrow) * HS + s * 32 + lk * 8);
#pragma unroll
    for (int nf = 0; nf < 2; ++nf)
      b[nf] = *(const f16x8*)(Wl + ((size_t)(s * 4 + lk) * 68 + wn * 32 + nf * 16 + lrow) * 8);
#pragma unroll
    for (int mf = 0; mf < 2; ++mf)
#pragma unroll
      for (int nf = 0; nf < 2; ++nf)
        acc2[mf][nf] = __builtin_amdgcn_mfma_f32_16x16x32_f16(a[mf], b[nf], acc2[mf][nf], 0, 0, 0);
  }
}

__global__ __launch_bounds__(256, 2) void phase1_kernel(
    const float* __restrict__ obs, const float* __restrict__ act,
    const float* __restrict__ V_W1, const float* __restrict__ V_b1,
    const float* __restrict__ V_W2, const float* __restrict__ V_b2,
    const float* __restrict__ A_W1, const float* __restrict__ A_b1,
    const float* __restrict__ A_W2, const float* __restrict__ A_b2,
    float* __restrict__ Q) {
  // Wraw: W1 double-buffer (2 x 8320 fp16) OR W2 (32*68*8 = 17408 fp16) — 34.8 KB
  __shared__ __align__(16) _Float16 Wraw[32 * 68 * 8];
  __shared__ __align__(16) _Float16 Xl[2][64 * XS];   // 10.2 KB
  __shared__ __align__(16) _Float16 hl[64 * HS];      // 33.8 KB   => total ~77 KB
  _Float16* Wl0 = Wraw;
  _Float16* Wl1 = Wraw + 4 * WS * 8;

  int tid = threadIdx.x;
  int l = tid & 63, w = tid >> 6;
  int lrow = l & 15, lk = l >> 4;
  int Nbase = w * 64;
  int wm = w >> 1, wn = w & 1;

  // bid -> (n, b0): all 4 b-blocks of a node share one XCD residue and land on
  // the same CU slot consecutively (weight L1/L2 reuse); 2 co-resident blocks
  // on a CU are the same node, different b0.
  int bid = blockIdx.x;
  int r = bid & 7, s = bid >> 3;
  int n = r * 32 + (s & 31);
  int b0 = (s >> 5) * 64;

  f32x4 acc2[2][2];
#pragma unroll
  for (int i = 0; i < 2; ++i)
#pragma unroll
    for (int j = 0; j < 2; ++j) acc2[i][j] = (f32x4){0.f, 0.f, 0.f, 0.f};

  f32x4 acc[4][4];

  // ---------------- V branch ----------------
#pragma unroll
  for (int m = 0; m < 4; ++m)
#pragma unroll
    for (int nf = 0; nf < 4; ++nf) acc[m][nf] = (f32x4){0.f, 0.f, 0.f, 0.f};
  run_gemm1<8>(obs, obs, V_W1 + (size_t)n * HD * HD, b0, n, tid, lrow, lk, Nbase,
               Xl[0], Xl[1], Wl0, Wl1, acc);
  h_write(hl, V_b1 + n * HD, w, lrow, lk, acc);
  __syncthreads();                         // hl visible; W1 reads done
  w2_stage(V_W2 + (size_t)n * HD * FD, tid, Wraw);
  __syncthreads();
  run_gemm2(hl, Wraw, wm, wn, lrow, lk, acc2);
  __syncthreads();                         // Wraw/hl reads done before A reuses them

  // ---------------- A branch ----------------
#pragma unroll
  for (int m = 0; m < 4; ++m)
#pragma unroll
    for (int nf = 0; nf < 4; ++nf) acc[m][nf] = (f32x4){0.f, 0.f, 0.f, 0.f};
  run_gemm1<16>(obs, act, A_W1 + (size_t)n * 2 * HD * HD, b0, n, tid, lrow, lk, Nbase,
                Xl[0], Xl[1], Wl0, Wl1, acc);
  h_write(hl, A_b1 + n * HD, w, lrow, lk, acc);
  __syncthreads();
  w2_stage(A_W2 + (size_t)n * HD * FD, tid, Wraw);
  __syncthreads();
  run_gemm2(hl, Wraw, wm, wn, lrow, lk, acc2);

  // ---------------- Q = acc2 + V_b2 + A_b2 ----------------
  const float* vb2 = V_b2 + n * FD;
  const float* ab2 = A_b2 + n * FD;
#pragma unroll
  for (int mf = 0; mf < 2; ++mf)
#pragma unroll
    for (int nf = 0; nf < 2; ++nf) {
      int f = wn * 32 + nf * 16 + lrow;
      float bias = vb2[f] + ab2[f];
#pragma unroll
      for (int rr = 0; rr < 4; ++rr) {
        int row = b0 + wm * 32 + mf * 16 + lk * 4 + rr;
        Q[(size_t)row * (BN * FD) + n * FD + f] = acc2[mf][nf][rr] + bias;
      }
    }
}

// ---------------- phase 2: gather + subset-min + chi + mean ----------------
__global__ __launch_bounds__(256) void phase2_kernel(const float* __restrict__ Q,
                                                     const float* __restrict__ chi_m,
                                                     const int* __restrict__ le,
                                                     float* __restrict__ out) {
  int b = blockIdx.x;
  int n = threadIdx.x;
  // int64-vs-int32 layout hedge: centers = arange(N) => int32 layout has
  // le[5]==1; int64 layout has a 0 high-word there.
  int step = (le[5] == 1) ? 1 : 2;
  const int* e = le + n * 5 * step;
  int c  = e[0 * step] & (BN - 1);
  int n0 = e[1 * step] & (BN - 1);
  int n1 = e[2 * step] & (BN - 1);
  int n2 = e[3 * step] & (BN - 1);
  int n3 = e[4 * step] & (BN - 1);
  const float* ch = chi_m + n * 45;         // (HEADS=3, S=15)
  float cm[15];
#pragma unroll
  for (int s = 0; s < 15; ++s) cm[s] = (ch[s] + ch[15 + s] + ch[30 + s]) * (1.f / 3.f);
  const float* qb = Q + (size_t)b * (BN * FD);
  const float* q0 = qb + n0 * FD;
  const float* q1 = qb + n1 * FD;
  const float* q2 = qb + n2 * FD;
  const float* q3 = qb + n3 * FD;
  const float* qc = qb + c * FD;
  float acc = 0.f;
#pragma unroll
  for (int f = 0; f < FD; f += 4) {
    float4 v0 = *(const float4*)(q0 + f);
    float4 v1 = *(const float4*)(q1 + f);
    float4 v2 = *(const float4*)(q2 + f);
    float4 v3 = *(const float4*)(q3 + f);
    float4 vc = *(const float4*)(qc + f);
    const float* p0 = (const float*)&v0;
    const float* p1 = (const float*)&v1;
    const float* p2 = (const float*)&v2;
    const float* p3 = (const float*)&v3;
    const float* pc = (const float*)&vc;
#pragma unroll
    for (int u = 0; u < 4; ++u) {
      float a = p0[u], bq = p1[u], cq = p2[u], d = p3[u];
      float m01 = fminf(a, bq), m02 = fminf(a, cq), m03 = fminf(a, d);
      float m12 = fminf(bq, cq), m13 = fminf(bq, d), m23 = fminf(cq, d);
      float m012 = fminf(m01, cq), m013 = fminf(m01, d);
      float m023 = fminf(m02, d),  m123 = fminf(m12, d);
      float m0123 = fminf(m01, m23);
      float chi = cm[0] * a   + cm[1] * bq   + cm[2] * m01  + cm[3] * cq
                + cm[4] * m02 + cm[5] * m12  + cm[6] * m012 + cm[7] * d
                + cm[8] * m03 + cm[9] * m13  + cm[10] * m013 + cm[11] * m23
                + cm[12] * m023 + cm[13] * m123 + cm[14] * m0123;
      acc += chi + pc[u];
    }
  }
  out[b * BN + n] = acc * (1.f / 64.f);
}

extern "C" void kernel_launch(void* const* d_in, const int* in_sizes, int n_in,
                              void* d_out, int out_size, void* d_ws, size_t ws_size,
                              hipStream_t stream) {
  (void)in_sizes; (void)n_in; (void)out_size; (void)ws_size;
  const float* obs  = (const float*)d_in[0];
  const float* act  = (const float*)d_in[1];
  const float* V_W1 = (const float*)d_in[2];
  const float* V_b1 = (const float*)d_in[3];
  const float* V_W2 = (const float*)d_in[4];
  const float* V_b2 = (const float*)d_in[5];
  const float* A_W1 = (const float*)d_in[6];
  const float* A_b1 = (const float*)d_in[7];
  const float* A_W2 = (const float*)d_in[8];
  const float* A_b2 = (const float*)d_in[9];
  const float* chim = (const float*)d_in[10];
  const int*   le   = (const int*)d_in[11];
  float* Q   = (float*)d_ws;                  // 16 MB scratch: Q[B][N][F]
  float* out = (float*)d_out;

  phase1_kernel<<<dim3(1024), dim3(256), 0, stream>>>(obs, act, V_W1, V_b1, V_W2, V_b2,
                                                      A_W1, A_b1, A_W2, A_b2, Q);
  phase2_kernel<<<dim3(256), dim3(256), 0, stream>>>(Q, chim, le, out);
}